// Round 20
// baseline (84.342 us; speedup 1.0000x reference)
//
#include <hip/hip_runtime.h>

typedef __attribute__((ext_vector_type(8))) short short8;
typedef __attribute__((ext_vector_type(4))) short short4v;
typedef __attribute__((ext_vector_type(4))) float f32x4;
typedef __attribute__((ext_vector_type(16))) float f32x16;
typedef __attribute__((ext_vector_type(4))) unsigned u32x4;

#define LOG2E 1.4426950408889634f

__device__ __forceinline__ float bf2f(short s) {
  union { unsigned u; float f; } cv;
  cv.u = ((unsigned)(unsigned short)s) << 16;
  return cv.f;
}
__device__ __forceinline__ short f2bf(float f) {
  union { float f; unsigned u; } cv;
  cv.f = f;
  unsigned r = (cv.u + 0x7fffu + ((cv.u >> 16) & 1u)) >> 16;
  return (short)(unsigned short)r;
}
// packed RNE f32x2 -> bf16x2 (lo = a, hi = b) in one VALU op
__device__ __forceinline__ unsigned cvtpk(float a, float b) {
  unsigned r;
  asm("v_cvt_pk_bf16_f32 %0, %1, %2" : "=v"(r) : "v"(a), "v"(b));
  return r;
}
// raw v_exp_f32: 2^x
__device__ __forceinline__ float fexp2(float x) {
  float r;
  asm("v_exp_f32 %0, %1" : "=v"(r) : "v"(x));
  return r;
}
// async global->LDS, 16B/lane, lane i lands at ldsbase + i*16
__device__ __forceinline__ void load_lds16(const void* g, void* l) {
  __builtin_amdgcn_global_load_lds(
      (const __attribute__((address_space(1))) void*)g,
      (__attribute__((address_space(3))) void*)l, 16, 0, 0);
}

#define MFMA16(a, b, c) __builtin_amdgcn_mfma_f32_16x16x32_bf16((a), (b), (c), 0, 0, 0)
#define MFMA32(a, b, c) __builtin_amdgcn_mfma_f32_32x32x16_bf16((a), (b), (c), 0, 0, 0)

// ---------------------------------------------------------------------------
// convert fp32 weight matrices -> bf16 workspace. 4 matrices x 32768 elems.
// ---------------------------------------------------------------------------
__global__ __launch_bounds__(256) void cvt_w(
    const float* __restrict__ s0, const float* __restrict__ s1,
    const float* __restrict__ s2, const float* __restrict__ s3,
    short* __restrict__ d)
{
  const float* srcs[4] = {s0, s1, s2, s3};
  const float* s = srcs[blockIdx.y];
  int i = (blockIdx.x * 256 + threadIdx.x) * 4;
  f32x4 v = *reinterpret_cast<const f32x4*>(s + i);
  short4v o;
  #pragma unroll
  for (int j = 0; j < 4; j++) o[j] = f2bf(v[j]);
  *reinterpret_cast<short4v*>(d + (size_t)blockIdx.y * 32768 + i) = o;
}

// ---------------------------------------------------------------------------
// conv1x1 body (+ optional fused 2x2 maxpool epilogues).  Pixel<->M-row
// permutation puts a pooled cell's 4 pixels in one lane's f32x4 (exact).
// MODE: 0 full-res [b][p][o] SCALED by log2e (theta feeds exp2-domain attn);
//       1 pooled [b][kp][o]; 2 pooled-T [b][o][kp].
// ---------------------------------------------------------------------------
template <int NPROJ, int MODE1>
__device__ __forceinline__ void conv_body(
    short (*in_t)[40], short (*wt)[40],
    const float* __restrict__ in,
    const short* __restrict__ w0, const float* __restrict__ bias0,
    const short* __restrict__ w1, const float* __restrict__ bias1,
    short* __restrict__ out0, short* __restrict__ out1)
{
  const int b = blockIdx.y;
  const int p0 = blockIdx.x * 128;
  const int tid = threadIdx.x;
  const int wave = tid >> 6, lane = tid & 63;
  const int lr = lane & 15, lg = lane >> 4;

  const short* wsrc[2] = {w0, w1};

  f32x4 acc[NPROJ][8];
  #pragma unroll
  for (int pj = 0; pj < NPROJ; pj++)
    #pragma unroll
    for (int n = 0; n < 8; n++) acc[pj][n] = (f32x4)0.0f;

  for (int kc = 0; kc < 256; kc += 32) {
    __syncthreads();
    {
      int c = tid >> 4;                 // 0..31
      int pg = (tid & 15) * 8;          // global pixel group 0..120
      const float* src = in + ((size_t)(b * 256 + kc + c)) * 4096 + p0 + pg;
      f32x4 v0 = *reinterpret_cast<const f32x4*>(src);
      f32x4 v1 = *reinterpret_cast<const f32x4*>(src + 4);
      #pragma unroll
      for (int j = 0; j < 8; j++) {
        int p = pg + j;
        int a = ((p & 63) >> 1) * 4 + ((p >> 6) << 1) + (p & 1);
        float fv = (j < 4) ? v0[j] : v1[j - 4];
        in_t[a][c ^ ((((a >> 3) & 3)) << 3)] = f2bf(fv);
      }
    }
    if (tid < NPROJ * 128) {
      int pj = tid >> 7, o = tid & 127;
      const short8* src = reinterpret_cast<const short8*>(wsrc[pj] + (size_t)o * 256 + kc);
      int f = (o >> 3) & 3;
      #pragma unroll
      for (int gq = 0; gq < 4; gq++)
        *reinterpret_cast<short8*>(&wt[pj * 128 + o][(gq ^ f) * 8]) = src[gq];
    }
    __syncthreads();

    int arow = wave * 16 + lr;
    short8 afrag = *reinterpret_cast<const short8*>(
        &in_t[arow][(lg ^ ((arow >> 3) & 3)) * 8]);
    #pragma unroll
    for (int pj = 0; pj < NPROJ; pj++) {
      #pragma unroll
      for (int n = 0; n < 8; n++) {
        int brow = n * 16 + lr;
        short8 bfrag = *reinterpret_cast<const short8*>(
            &wt[pj * 128 + brow][(lg ^ ((brow >> 3) & 3)) * 8]);
        acc[pj][n] = MFMA16(afrag, bfrag, acc[pj][n]);
      }
    }
  }

  const float* bsrc[2] = {bias0, bias1};
  short* osrc[2] = {out0, out1};
  const int kp = blockIdx.x * 32 + wave * 4 + lg;
  #pragma unroll
  for (int pj = 0; pj < NPROJ; pj++) {
    const int mode = (pj == 0 && NPROJ == 2) ? 0 : MODE1;
    #pragma unroll
    for (int n = 0; n < 8; n++) {
      int o = n * 16 + lr;
      float bv = bsrc[pj][o];
      if (mode == 0) {
        #pragma unroll
        for (int r = 0; r < 4; r++) {
          int pix = (wave * 4 + lg) * 2 + (r & 1) + ((r >> 1) & 1) * 64;
          osrc[pj][((size_t)b * 4096 + p0 + pix) * 128 + o] =
              f2bf((acc[pj][n][r] + bv) * LOG2E);
        }
      } else {
        f32x4 v = acc[pj][n];
        float pv = fmaxf(fmaxf(v[0], v[1]), fmaxf(v[2], v[3])) + bv;
        if (mode == 1)
          osrc[pj][((size_t)b * 1024 + kp) * 128 + o] = f2bf(pv);
        else
          osrc[pj][((size_t)b * 128 + o) * 1024 + kp] = f2bf(pv);
      }
    }
  }
}

// fused conv dispatch: z=0 -> theta(full, xlog2e)+phi(pooled) from nb;
//                      z=1 -> g (pooled-T) from x.
// launch_bounds (512, 4): R10-R13 empirical best.
__global__ __launch_bounds__(512, 4) void conv_all(
    const float* __restrict__ nb, const float* __restrict__ x,
    const short* __restrict__ th_w, const float* __restrict__ th_b,
    const short* __restrict__ ph_w, const float* __restrict__ ph_b,
    const short* __restrict__ g_w, const float* __restrict__ g_b,
    short* __restrict__ theta, short* __restrict__ phi_kc,
    short* __restrict__ g_ck)
{
  __shared__ short in_t[128][40];
  __shared__ short wt[256][40];
  if (blockIdx.z == 0)
    conv_body<2, 1>(in_t, wt, nb, th_w, th_b, ph_w, ph_b, theta, phi_kc);
  else
    conv_body<1, 2>(in_t, wt, x, g_w, g_b, nullptr, nullptr, g_ck, nullptr);
}

// ---------------------------------------------------------------------------
// FUSED flash attention + W-conv + BN + residual (R13 structure; W-GEMM
// epilogue re-oriented to C[q][co] so stores/loads vectorize as float4).
// Phase A (attn): in-block split-KV (waves 0-3 kv[0,512), 4-7 kv[512,1024)),
//   32x32 MFMA, gload_lds staging (pre-swizzled src), exp2 domain,
//   in-register P.  Phase B: merge halves -> y tile bf16 in LDS ->
//   8-wave GEMM (A = y_s q rows, B = ww co rows) + BN + residual, float4 I/O.
// Grid (32, 8) = 256 blocks, 512 threads.
// ---------------------------------------------------------------------------
__global__ __launch_bounds__(512) void attn_wconv(
    const short* __restrict__ theta, const short* __restrict__ phi,
    const short* __restrict__ g, const short* __restrict__ ww,
    const float* __restrict__ wb,
    const float* __restrict__ gamma, const float* __restrict__ beta,
    const float* __restrict__ mean, const float* __restrict__ var,
    const float* __restrict__ x, float* __restrict__ out)
{
  __shared__ char lds[131072];          // attn: phi bufs 0-64K, g bufs 64-128K
                                        // post: mb 0-64K, y_s @64K, sc/sh @112K
  __shared__ float ml[8][32][2];

  const int b = blockIdx.y;
  const int q0 = blockIdx.x * 128;
  const int tid = threadIdx.x;
  const int wave = tid >> 6, lane = tid & 63;
  const int l31 = lane & 31, hi = lane >> 5;
  const int zw = wave >> 2, wq = wave & 3;

  // theta B-fragments (theta pre-scaled by log2e)
  short8 ath[8];
  {
    const short* tq = theta + ((size_t)b * 4096 + q0 + wq * 32 + l31) * 128 + hi * 8;
    #pragma unroll
    for (int s = 0; s < 8; s++)
      ath[s] = *reinterpret_cast<const short8*>(tq + s * 16);
  }

  // gload_lds staging (pre-swizzled global src, linear LDS dest)
  const short* psrc[4];
  {
    int rb = wq * 16 + (lane >> 4), sl = lane & 15;
    #pragma unroll
    for (int i = 0; i < 4; i++) {
      int r = rb + i * 4;
      psrc[i] = phi + ((size_t)b * 1024 + zw * 512 + r) * 128 + ((sl ^ (r & 15)) * 8);
    }
  }
  const short* gsrc[4];
  {
    int rb = wq * 32 + (lane >> 3), sl = lane & 7;
    #pragma unroll
    for (int i = 0; i < 4; i++) {
      int r = rb + i * 8;
      gsrc[i] = g + ((size_t)b * 128 + r) * 1024 + zw * 512 + ((sl ^ (r & 7)) * 8);
    }
  }

  float mrun = -1e30f, lpart = 0.0f;
  f32x16 acc[4];
  #pragma unroll
  for (int n = 0; n < 4; n++) acc[n] = (f32x16)0.0f;

  {
    char* pb = lds + zw * 16384 + wq * 4096;
    char* gb = lds + 65536 + zw * 16384 + wq * 4096;
    #pragma unroll
    for (int i = 0; i < 4; i++) {
      load_lds16(psrc[i], pb + i * 1024);
      load_lds16(gsrc[i], gb + i * 1024);
    }
  }

  for (int t = 0; t < 8; t++) {
    __syncthreads();
    char* pb = lds + ((t & 1) * 2 + zw) * 16384;
    char* gb = lds + 65536 + ((t & 1) * 2 + zw) * 16384;

    if (t < 7) {
      char* pb2 = lds + (((t + 1) & 1) * 2 + zw) * 16384 + wq * 4096;
      char* gb2 = lds + 65536 + (((t + 1) & 1) * 2 + zw) * 16384 + wq * 4096;
      #pragma unroll
      for (int i = 0; i < 4; i++) {
        load_lds16(psrc[i] + (t + 1) * 8192, pb2 + i * 1024);
        load_lds16(gsrc[i] + (t + 1) * 64, gb2 + i * 1024);
      }
    }

    // QK^T (S' in log2 units)
    f32x16 facc0 = (f32x16)0.0f, facc1 = (f32x16)0.0f;
    __builtin_amdgcn_s_setprio(1);
    #pragma unroll
    for (int s = 0; s < 8; s++) {
      int slot = (s << 1) | hi;
      short8 pf0 = *reinterpret_cast<const short8*>(
          pb + l31 * 256 + ((slot ^ (l31 & 15)) * 16));
      short8 pf1 = *reinterpret_cast<const short8*>(
          pb + (32 + l31) * 256 + ((slot ^ (l31 & 15)) * 16));
      facc0 = MFMA32(pf0, ath[s], facc0);
      facc1 = MFMA32(pf1, ath[s], facc1);
    }
    __builtin_amdgcn_s_setprio(0);

    // online softmax in exp2 domain; depth-5 trees
    float mv[16];
    #pragma unroll
    for (int r = 0; r < 16; r++) mv[r] = fmaxf(facc0[r], facc1[r]);
    #pragma unroll
    for (int s = 8; s >= 1; s >>= 1)
      #pragma unroll
      for (int r = 0; r < s; r++) mv[r] = fmaxf(mv[r], mv[r + s]);
    float m = fmaxf(mv[0], __shfl_xor(mv[0], 32));

    if (__any(m - mrun > 14.0f)) {
      float mn = fmaxf(mrun, m);
      float sc = fexp2(mrun - mn);
      mrun = mn;
      lpart *= sc;
      #pragma unroll
      for (int reg = 0; reg < 16; reg++) {
        int qr = (reg & 3) + 8 * (reg >> 2) + 4 * hi;
        float sr = __shfl(sc, qr);
        #pragma unroll
        for (int n = 0; n < 4; n++) acc[n][reg] *= sr;
      }
    }
    #pragma unroll
    for (int r = 0; r < 16; r++) facc0[r] = fexp2(facc0[r] - mrun);
    #pragma unroll
    for (int r = 0; r < 16; r++) facc1[r] = fexp2(facc1[r] - mrun);
    {
      float sv[16];
      #pragma unroll
      for (int r = 0; r < 16; r++) sv[r] = facc0[r] + facc1[r];
      #pragma unroll
      for (int s = 8; s >= 1; s >>= 1)
        #pragma unroll
        for (int r = 0; r < s; r++) sv[r] += sv[r + s];
      lpart += sv[0];
    }

    // PV with in-register P assembly
    __builtin_amdgcn_s_setprio(1);
    #pragma unroll
    for (int s = 0; s < 4; s++) {
      const int base = (s & 1) * 8;
      float p0, p1, p2, p3, p4, p5, p6, p7;
      if (s < 2) {
        p0 = facc0[base + 0]; p1 = facc0[base + 1]; p2 = facc0[base + 2]; p3 = facc0[base + 3];
        p4 = facc0[base + 4]; p5 = facc0[base + 5]; p6 = facc0[base + 6]; p7 = facc0[base + 7];
      } else {
        p0 = facc1[base + 0]; p1 = facc1[base + 1]; p2 = facc1[base + 2]; p3 = facc1[base + 3];
        p4 = facc1[base + 4]; p5 = facc1[base + 5]; p6 = facc1[base + 6]; p7 = facc1[base + 7];
      }
      unsigned P0w0 = cvtpk(p0, p1), P0w1 = cvtpk(p2, p3);
      unsigned P1w0 = cvtpk(p4, p5), P1w1 = cvtpk(p6, p7);
      unsigned x0 = (unsigned)__shfl_xor((int)P0w0, 32);
      unsigned x1 = (unsigned)__shfl_xor((int)P0w1, 32);
      unsigned y0 = (unsigned)__shfl_xor((int)P1w0, 32);
      unsigned y1 = (unsigned)__shfl_xor((int)P1w1, 32);
      union { u32x4 u; short8 s8; } pf;
      pf.u[0] = hi ? y0 : P0w0;
      pf.u[1] = hi ? y1 : P0w1;
      pf.u[2] = hi ? P1w0 : x0;
      pf.u[3] = hi ? P1w1 : x1;
      int slot = (s << 1) | hi;
      #pragma unroll
      for (int n = 0; n < 4; n++) {
        int rg = n * 32 + l31;
        short8 gf = *reinterpret_cast<const short8*>(
            gb + rg * 128 + ((slot ^ (rg & 7)) * 16));
        acc[n] = MFMA32(pf.s8, gf, acc[n]);
      }
    }
    __builtin_amdgcn_s_setprio(0);
  }

  // ---- Phase B ----
  float lsum = lpart + __shfl_xor(lpart, 32);
  if (lane < 32) { ml[wave][l31][0] = mrun; ml[wave][l31][1] = lsum; }
  __syncthreads();   // ALL loop-phase LDS reads complete; overlays now safe

  float* sc_s = (float*)(lds + 114688);
  float* sh_s = (float*)(lds + 118784);
  if (tid < 256) {
    float s = gamma[tid] * rsqrtf(var[tid] + 1e-5f);
    sc_s[tid] = s;
    sh_s[tid] = (wb[tid] - mean[tid]) * s + beta[tid];
  }

  float mo = ml[wave ^ 4][l31][0];
  float lo = ml[wave ^ 4][l31][1];
  float M = fmaxf(mrun, mo);
  float e0 = fexp2(mrun - M), e1 = fexp2(mo - M);
  float wown = e0 / (e0 * lsum + e1 * lo);
  #pragma unroll
  for (int reg = 0; reg < 16; reg++) {
    int qr = (reg & 3) + 8 * (reg >> 2) + 4 * hi;
    float wr = __shfl(wown, qr);
    #pragma unroll
    for (int n = 0; n < 4; n++) acc[n][reg] *= wr;
  }
  float* mb = (float*)(lds + wq * 16384);    // fp32 exchange, overlays phi bufs
  if (zw == 1) {
    #pragma unroll
    for (int n = 0; n < 4; n++)
      #pragma unroll
      for (int reg = 0; reg < 16; reg++) {
        int qrow = (reg & 3) + 8 * (reg >> 2) + 4 * hi;
        mb[qrow * 128 + n * 32 + l31] = acc[n][reg];
      }
  }
  __syncthreads();
  short* y_s = (short*)(lds + 65536);        // [128][136] bf16, overlays g bufs
  if (zw == 0) {
    #pragma unroll
    for (int n = 0; n < 4; n++)
      #pragma unroll
      for (int reg = 0; reg < 16; reg++) {
        int qrow = (reg & 3) + 8 * (reg >> 2) + 4 * hi;
        float v = acc[n][reg] + mb[qrow * 128 + n * 32 + l31];
        y_s[(wq * 32 + qrow) * 136 + n * 32 + l31] = f2bf(v);
      }
  }
  __syncthreads();

  // ---- W-GEMM, transposed orientation: C[q][co] ----
  // A = y_s rows (q), B = ww rows (co).  Wave owns q rows wave*16 + 0..15.
  // Output: thread (lr,lg) holds C[q = wave*16 + lg*4 + r][co = n*16 + lr]
  // -> 4 consecutive q at fixed co -> float4 stores/loads for out and x.
  const int lr = lane & 15, lg = lane >> 4;
  f32x4 acc2[16];
  #pragma unroll
  for (int n = 0; n < 16; n++) acc2[n] = (f32x4)0.0f;

  #pragma unroll
  for (int kk = 0; kk < 4; kk++) {
    short8 af = *reinterpret_cast<const short8*>(
        &y_s[(wave * 16 + lr) * 136 + kk * 32 + lg * 8]);
    #pragma unroll
    for (int h = 0; h < 2; h++) {
      short8 bfr[8];
      #pragma unroll
      for (int j = 0; j < 8; j++)
        bfr[j] = *reinterpret_cast<const short8*>(
            ww + (size_t)((h * 8 + j) * 16 + lr) * 128 + kk * 32 + lg * 8);
      #pragma unroll
      for (int j = 0; j < 8; j++)
        acc2[h * 8 + j] = MFMA16(af, bfr[j], acc2[h * 8 + j]);
    }
  }

  #pragma unroll
  for (int n = 0; n < 16; n++) {
    int co = n * 16 + lr;
    int q = q0 + wave * 16 + lg * 4;
    size_t oidx = ((size_t)b * 256 + co) * 4096 + q;
    f32x4 xv = *reinterpret_cast<const f32x4*>(x + oidx);
    float sc = sc_s[co], sh = sh_s[co];
    f32x4 v;
    #pragma unroll
    for (int r = 0; r < 4; r++) v[r] = acc2[n][r] * sc + sh + xv[r];
    *reinterpret_cast<f32x4*>(out + oidx) = v;
  }
}

// ---------------------------------------------------------------------------
extern "C" void kernel_launch(void* const* d_in, const int* in_sizes, int n_in,
                              void* d_out, int out_size, void* d_ws, size_t ws_size,
                              hipStream_t stream)
{
  const float* x    = (const float*)d_in[0];
  const float* nb   = (const float*)d_in[1];
  const float* g_w  = (const float*)d_in[2];
  const float* g_b  = (const float*)d_in[3];
  const float* th_w = (const float*)d_in[4];
  const float* th_b = (const float*)d_in[5];
  const float* ph_w = (const float*)d_in[6];
  const float* ph_b = (const float*)d_in[7];
  const float* w_w  = (const float*)d_in[8];
  const float* w_b  = (const float*)d_in[9];
  const float* gam  = (const float*)d_in[10];
  const float* bet  = (const float*)d_in[11];
  const float* mu   = (const float*)d_in[12];
  const float* var  = (const float*)d_in[13];
  float* out = (float*)d_out;

  char* ws = (char*)d_ws;
  short* theta_full = (short*)(ws);                        // 8 MB  [b][4096][128]
  short* phi_kc     = (short*)(ws + (size_t)(8u << 20));   // 2 MB  [b][1024][128]
  short* g_ck       = (short*)(ws + (size_t)(10u << 20));  // 2 MB  [b][128][1024]
  short* wts        = (short*)(ws + (size_t)(12u << 20));  // 256KB: th, ph, g, w
  short* th_wb = wts;
  short* ph_wb = wts + 32768;
  short* g_wb  = wts + 2 * 32768;
  short* w_wb  = wts + 3 * 32768;

  cvt_w<<<dim3(32, 4), 256, 0, stream>>>(th_w, ph_w, g_w, w_w, wts);
  conv_all<<<dim3(32, 8, 2), 512, 0, stream>>>(nb, x, th_wb, th_b, ph_wb, ph_b,
                                               g_wb, g_b, theta_full, phi_kc, g_ck);
  attn_wconv<<<dim3(32, 8), 512, 0, stream>>>(theta_full, phi_kc, g_ck, w_wb, w_b,
                                              gam, bet, mu, var, x, out);
}

// Round 21
// 74.580 us; speedup vs baseline: 1.1309x; 1.1309x over previous
//
#include <hip/hip_runtime.h>

typedef __attribute__((ext_vector_type(8))) short short8;
typedef __attribute__((ext_vector_type(4))) short short4v;
typedef __attribute__((ext_vector_type(4))) float f32x4;
typedef __attribute__((ext_vector_type(16))) float f32x16;
typedef __attribute__((ext_vector_type(4))) unsigned u32x4;

#define LOG2E 1.4426950408889634f

__device__ __forceinline__ float bf2f(short s) {
  union { unsigned u; float f; } cv;
  cv.u = ((unsigned)(unsigned short)s) << 16;
  return cv.f;
}
__device__ __forceinline__ short f2bf(float f) {
  union { float f; unsigned u; } cv;
  cv.f = f;
  unsigned r = (cv.u + 0x7fffu + ((cv.u >> 16) & 1u)) >> 16;
  return (short)(unsigned short)r;
}
// packed RNE f32x2 -> bf16x2 (lo = a, hi = b) in one VALU op
__device__ __forceinline__ unsigned cvtpk(float a, float b) {
  unsigned r;
  asm("v_cvt_pk_bf16_f32 %0, %1, %2" : "=v"(r) : "v"(a), "v"(b));
  return r;
}
// raw v_exp_f32: 2^x
__device__ __forceinline__ float fexp2(float x) {
  float r;
  asm("v_exp_f32 %0, %1" : "=v"(r) : "v"(x));
  return r;
}
// async global->LDS, 16B/lane, lane i lands at ldsbase + i*16
__device__ __forceinline__ void load_lds16(const void* g, void* l) {
  __builtin_amdgcn_global_load_lds(
      (const __attribute__((address_space(1))) void*)g,
      (__attribute__((address_space(3))) void*)l, 16, 0, 0);
}

#define MFMA16(a, b, c) __builtin_amdgcn_mfma_f32_16x16x32_bf16((a), (b), (c), 0, 0, 0)
#define MFMA32(a, b, c) __builtin_amdgcn_mfma_f32_32x32x16_bf16((a), (b), (c), 0, 0, 0)

// ---------------------------------------------------------------------------
// convert fp32 weight matrices -> bf16 workspace. 4 matrices x 32768 elems.
// ---------------------------------------------------------------------------
__global__ __launch_bounds__(256) void cvt_w(
    const float* __restrict__ s0, const float* __restrict__ s1,
    const float* __restrict__ s2, const float* __restrict__ s3,
    short* __restrict__ d)
{
  const float* srcs[4] = {s0, s1, s2, s3};
  const float* s = srcs[blockIdx.y];
  int i = (blockIdx.x * 256 + threadIdx.x) * 4;
  f32x4 v = *reinterpret_cast<const f32x4*>(s + i);
  short4v o;
  #pragma unroll
  for (int j = 0; j < 4; j++) o[j] = f2bf(v[j]);
  *reinterpret_cast<short4v*>(d + (size_t)blockIdx.y * 32768 + i) = o;
}

// ---------------------------------------------------------------------------
// conv1x1 body (+ optional fused 2x2 maxpool epilogues).  Pixel<->M-row
// permutation puts a pooled cell's 4 pixels in one lane's f32x4 (exact).
// MODE: 0 full-res [b][p][o] SCALED by log2e (theta feeds exp2-domain attn);
//       1 pooled [b][kp][o]; 2 pooled-T [b][o][kp].
// ---------------------------------------------------------------------------
template <int NPROJ, int MODE1>
__device__ __forceinline__ void conv_body(
    short (*in_t)[40], short (*wt)[40],
    const float* __restrict__ in,
    const short* __restrict__ w0, const float* __restrict__ bias0,
    const short* __restrict__ w1, const float* __restrict__ bias1,
    short* __restrict__ out0, short* __restrict__ out1)
{
  const int b = blockIdx.y;
  const int p0 = blockIdx.x * 128;
  const int tid = threadIdx.x;
  const int wave = tid >> 6, lane = tid & 63;
  const int lr = lane & 15, lg = lane >> 4;

  const short* wsrc[2] = {w0, w1};

  f32x4 acc[NPROJ][8];
  #pragma unroll
  for (int pj = 0; pj < NPROJ; pj++)
    #pragma unroll
    for (int n = 0; n < 8; n++) acc[pj][n] = (f32x4)0.0f;

  for (int kc = 0; kc < 256; kc += 32) {
    __syncthreads();
    {
      int c = tid >> 4;                 // 0..31
      int pg = (tid & 15) * 8;          // global pixel group 0..120
      const float* src = in + ((size_t)(b * 256 + kc + c)) * 4096 + p0 + pg;
      f32x4 v0 = *reinterpret_cast<const f32x4*>(src);
      f32x4 v1 = *reinterpret_cast<const f32x4*>(src + 4);
      #pragma unroll
      for (int j = 0; j < 8; j++) {
        int p = pg + j;
        int a = ((p & 63) >> 1) * 4 + ((p >> 6) << 1) + (p & 1);
        float fv = (j < 4) ? v0[j] : v1[j - 4];
        in_t[a][c ^ ((((a >> 3) & 3)) << 3)] = f2bf(fv);
      }
    }
    if (tid < NPROJ * 128) {
      int pj = tid >> 7, o = tid & 127;
      const short8* src = reinterpret_cast<const short8*>(wsrc[pj] + (size_t)o * 256 + kc);
      int f = (o >> 3) & 3;
      #pragma unroll
      for (int gq = 0; gq < 4; gq++)
        *reinterpret_cast<short8*>(&wt[pj * 128 + o][(gq ^ f) * 8]) = src[gq];
    }
    __syncthreads();

    int arow = wave * 16 + lr;
    short8 afrag = *reinterpret_cast<const short8*>(
        &in_t[arow][(lg ^ ((arow >> 3) & 3)) * 8]);
    #pragma unroll
    for (int pj = 0; pj < NPROJ; pj++) {
      #pragma unroll
      for (int n = 0; n < 8; n++) {
        int brow = n * 16 + lr;
        short8 bfrag = *reinterpret_cast<const short8*>(
            &wt[pj * 128 + brow][(lg ^ ((brow >> 3) & 3)) * 8]);
        acc[pj][n] = MFMA16(afrag, bfrag, acc[pj][n]);
      }
    }
  }

  const float* bsrc[2] = {bias0, bias1};
  short* osrc[2] = {out0, out1};
  const int kp = blockIdx.x * 32 + wave * 4 + lg;
  #pragma unroll
  for (int pj = 0; pj < NPROJ; pj++) {
    const int mode = (pj == 0 && NPROJ == 2) ? 0 : MODE1;
    #pragma unroll
    for (int n = 0; n < 8; n++) {
      int o = n * 16 + lr;
      float bv = bsrc[pj][o];
      if (mode == 0) {
        #pragma unroll
        for (int r = 0; r < 4; r++) {
          int pix = (wave * 4 + lg) * 2 + (r & 1) + ((r >> 1) & 1) * 64;
          osrc[pj][((size_t)b * 4096 + p0 + pix) * 128 + o] =
              f2bf((acc[pj][n][r] + bv) * LOG2E);
        }
      } else {
        f32x4 v = acc[pj][n];
        float pv = fmaxf(fmaxf(v[0], v[1]), fmaxf(v[2], v[3])) + bv;
        if (mode == 1)
          osrc[pj][((size_t)b * 1024 + kp) * 128 + o] = f2bf(pv);
        else
          osrc[pj][((size_t)b * 128 + o) * 1024 + kp] = f2bf(pv);
      }
    }
  }
}

// fused conv dispatch: z=0 -> theta(full, xlog2e)+phi(pooled) from nb;
//                      z=1 -> g (pooled-T) from x.
// launch_bounds (512, 4): R10-R13/R19 empirical best.
__global__ __launch_bounds__(512, 4) void conv_all(
    const float* __restrict__ nb, const float* __restrict__ x,
    const short* __restrict__ th_w, const float* __restrict__ th_b,
    const short* __restrict__ ph_w, const float* __restrict__ ph_b,
    const short* __restrict__ g_w, const float* __restrict__ g_b,
    short* __restrict__ theta, short* __restrict__ phi_kc,
    short* __restrict__ g_ck)
{
  __shared__ short in_t[128][40];
  __shared__ short wt[256][40];
  if (blockIdx.z == 0)
    conv_body<2, 1>(in_t, wt, nb, th_w, th_b, ph_w, ph_b, theta, phi_kc);
  else
    conv_body<1, 2>(in_t, wt, x, g_w, g_b, nullptr, nullptr, g_ck, nullptr);
}

// ---------------------------------------------------------------------------
// FUSED flash attention + W-conv + BN + residual (R13/R19 known-good).
// Phase A (attn): in-block split-KV (waves 0-3 kv[0,512), 4-7 kv[512,1024)),
//   32x32 MFMA, gload_lds staging (pre-swizzled src), exp2 domain,
//   in-register P.  Phase B: merge halves -> y tile bf16 in LDS ->
//   8-wave GEMM wy = w.y, BN, +x -> out fp32 (C[co][q] orientation:
//   R20's transposed variant regressed — ww re-reads beat the store win).
// Grid (32, 8) = 256 blocks, 512 threads.
// ---------------------------------------------------------------------------
__global__ __launch_bounds__(512) void attn_wconv(
    const short* __restrict__ theta, const short* __restrict__ phi,
    const short* __restrict__ g, const short* __restrict__ ww,
    const float* __restrict__ wb,
    const float* __restrict__ gamma, const float* __restrict__ beta,
    const float* __restrict__ mean, const float* __restrict__ var,
    const float* __restrict__ x, float* __restrict__ out)
{
  __shared__ char lds[131072];          // attn: phi bufs 0-64K, g bufs 64-128K
                                        // post: mb 0-64K, y_s @64K, sc/sh @112K
  __shared__ float ml[8][32][2];

  const int b = blockIdx.y;
  const int q0 = blockIdx.x * 128;
  const int tid = threadIdx.x;
  const int wave = tid >> 6, lane = tid & 63;
  const int l31 = lane & 31, hi = lane >> 5;
  const int zw = wave >> 2, wq = wave & 3;

  // theta B-fragments (theta pre-scaled by log2e)
  short8 ath[8];
  {
    const short* tq = theta + ((size_t)b * 4096 + q0 + wq * 32 + l31) * 128 + hi * 8;
    #pragma unroll
    for (int s = 0; s < 8; s++)
      ath[s] = *reinterpret_cast<const short8*>(tq + s * 16);
  }

  // gload_lds staging (pre-swizzled global src, linear LDS dest)
  const short* psrc[4];
  {
    int rb = wq * 16 + (lane >> 4), sl = lane & 15;
    #pragma unroll
    for (int i = 0; i < 4; i++) {
      int r = rb + i * 4;
      psrc[i] = phi + ((size_t)b * 1024 + zw * 512 + r) * 128 + ((sl ^ (r & 15)) * 8);
    }
  }
  const short* gsrc[4];
  {
    int rb = wq * 32 + (lane >> 3), sl = lane & 7;
    #pragma unroll
    for (int i = 0; i < 4; i++) {
      int r = rb + i * 8;
      gsrc[i] = g + ((size_t)b * 128 + r) * 1024 + zw * 512 + ((sl ^ (r & 7)) * 8);
    }
  }

  float mrun = -1e30f, lpart = 0.0f;
  f32x16 acc[4];
  #pragma unroll
  for (int n = 0; n < 4; n++) acc[n] = (f32x16)0.0f;

  {
    char* pb = lds + zw * 16384 + wq * 4096;
    char* gb = lds + 65536 + zw * 16384 + wq * 4096;
    #pragma unroll
    for (int i = 0; i < 4; i++) {
      load_lds16(psrc[i], pb + i * 1024);
      load_lds16(gsrc[i], gb + i * 1024);
    }
  }

  for (int t = 0; t < 8; t++) {
    __syncthreads();
    char* pb = lds + ((t & 1) * 2 + zw) * 16384;
    char* gb = lds + 65536 + ((t & 1) * 2 + zw) * 16384;

    if (t < 7) {
      char* pb2 = lds + (((t + 1) & 1) * 2 + zw) * 16384 + wq * 4096;
      char* gb2 = lds + 65536 + (((t + 1) & 1) * 2 + zw) * 16384 + wq * 4096;
      #pragma unroll
      for (int i = 0; i < 4; i++) {
        load_lds16(psrc[i] + (t + 1) * 8192, pb2 + i * 1024);
        load_lds16(gsrc[i] + (t + 1) * 64, gb2 + i * 1024);
      }
    }

    // QK^T (S' in log2 units)
    f32x16 facc0 = (f32x16)0.0f, facc1 = (f32x16)0.0f;
    __builtin_amdgcn_s_setprio(1);
    #pragma unroll
    for (int s = 0; s < 8; s++) {
      int slot = (s << 1) | hi;
      short8 pf0 = *reinterpret_cast<const short8*>(
          pb + l31 * 256 + ((slot ^ (l31 & 15)) * 16));
      short8 pf1 = *reinterpret_cast<const short8*>(
          pb + (32 + l31) * 256 + ((slot ^ (l31 & 15)) * 16));
      facc0 = MFMA32(pf0, ath[s], facc0);
      facc1 = MFMA32(pf1, ath[s], facc1);
    }
    __builtin_amdgcn_s_setprio(0);

    // online softmax in exp2 domain; depth-5 trees
    float mv[16];
    #pragma unroll
    for (int r = 0; r < 16; r++) mv[r] = fmaxf(facc0[r], facc1[r]);
    #pragma unroll
    for (int s = 8; s >= 1; s >>= 1)
      #pragma unroll
      for (int r = 0; r < s; r++) mv[r] = fmaxf(mv[r], mv[r + s]);
    float m = fmaxf(mv[0], __shfl_xor(mv[0], 32));

    if (__any(m - mrun > 14.0f)) {
      float mn = fmaxf(mrun, m);
      float sc = fexp2(mrun - mn);
      mrun = mn;
      lpart *= sc;
      #pragma unroll
      for (int reg = 0; reg < 16; reg++) {
        int qr = (reg & 3) + 8 * (reg >> 2) + 4 * hi;
        float sr = __shfl(sc, qr);
        #pragma unroll
        for (int n = 0; n < 4; n++) acc[n][reg] *= sr;
      }
    }
    #pragma unroll
    for (int r = 0; r < 16; r++) facc0[r] = fexp2(facc0[r] - mrun);
    #pragma unroll
    for (int r = 0; r < 16; r++) facc1[r] = fexp2(facc1[r] - mrun);
    {
      float sv[16];
      #pragma unroll
      for (int r = 0; r < 16; r++) sv[r] = facc0[r] + facc1[r];
      #pragma unroll
      for (int s = 8; s >= 1; s >>= 1)
        #pragma unroll
        for (int r = 0; r < s; r++) sv[r] += sv[r + s];
      lpart += sv[0];
    }

    // PV with in-register P assembly
    __builtin_amdgcn_s_setprio(1);
    #pragma unroll
    for (int s = 0; s < 4; s++) {
      const int base = (s & 1) * 8;
      float p0, p1, p2, p3, p4, p5, p6, p7;
      if (s < 2) {
        p0 = facc0[base + 0]; p1 = facc0[base + 1]; p2 = facc0[base + 2]; p3 = facc0[base + 3];
        p4 = facc0[base + 4]; p5 = facc0[base + 5]; p6 = facc0[base + 6]; p7 = facc0[base + 7];
      } else {
        p0 = facc1[base + 0]; p1 = facc1[base + 1]; p2 = facc1[base + 2]; p3 = facc1[base + 3];
        p4 = facc1[base + 4]; p5 = facc1[base + 5]; p6 = facc1[base + 6]; p7 = facc1[base + 7];
      }
      unsigned P0w0 = cvtpk(p0, p1), P0w1 = cvtpk(p2, p3);
      unsigned P1w0 = cvtpk(p4, p5), P1w1 = cvtpk(p6, p7);
      unsigned x0 = (unsigned)__shfl_xor((int)P0w0, 32);
      unsigned x1 = (unsigned)__shfl_xor((int)P0w1, 32);
      unsigned y0 = (unsigned)__shfl_xor((int)P1w0, 32);
      unsigned y1 = (unsigned)__shfl_xor((int)P1w1, 32);
      union { u32x4 u; short8 s8; } pf;
      pf.u[0] = hi ? y0 : P0w0;
      pf.u[1] = hi ? y1 : P0w1;
      pf.u[2] = hi ? P1w0 : x0;
      pf.u[3] = hi ? P1w1 : x1;
      int slot = (s << 1) | hi;
      #pragma unroll
      for (int n = 0; n < 4; n++) {
        int rg = n * 32 + l31;
        short8 gf = *reinterpret_cast<const short8*>(
            gb + rg * 128 + ((slot ^ (rg & 7)) * 16));
        acc[n] = MFMA32(pf.s8, gf, acc[n]);
      }
    }
    __builtin_amdgcn_s_setprio(0);
  }

  // ---- Phase B ----
  float lsum = lpart + __shfl_xor(lpart, 32);
  if (lane < 32) { ml[wave][l31][0] = mrun; ml[wave][l31][1] = lsum; }
  __syncthreads();   // ALL loop-phase LDS reads complete; overlays now safe

  float* sc_s = (float*)(lds + 114688);
  float* sh_s = (float*)(lds + 118784);
  if (tid < 256) {
    float s = gamma[tid] * rsqrtf(var[tid] + 1e-5f);
    sc_s[tid] = s;
    sh_s[tid] = (wb[tid] - mean[tid]) * s + beta[tid];
  }

  float mo = ml[wave ^ 4][l31][0];
  float lo = ml[wave ^ 4][l31][1];
  float M = fmaxf(mrun, mo);
  float e0 = fexp2(mrun - M), e1 = fexp2(mo - M);
  float wown = e0 / (e0 * lsum + e1 * lo);
  #pragma unroll
  for (int reg = 0; reg < 16; reg++) {
    int qr = (reg & 3) + 8 * (reg >> 2) + 4 * hi;
    float wr = __shfl(wown, qr);
    #pragma unroll
    for (int n = 0; n < 4; n++) acc[n][reg] *= wr;
  }
  float* mb = (float*)(lds + wq * 16384);    // fp32 exchange, overlays phi bufs
  if (zw == 1) {
    #pragma unroll
    for (int n = 0; n < 4; n++)
      #pragma unroll
      for (int reg = 0; reg < 16; reg++) {
        int qrow = (reg & 3) + 8 * (reg >> 2) + 4 * hi;
        mb[qrow * 128 + n * 32 + l31] = acc[n][reg];
      }
  }
  __syncthreads();
  short* y_s = (short*)(lds + 65536);        // [128][136] bf16, overlays g bufs
  if (zw == 0) {
    #pragma unroll
    for (int n = 0; n < 4; n++)
      #pragma unroll
      for (int reg = 0; reg < 16; reg++) {
        int qrow = (reg & 3) + 8 * (reg >> 2) + 4 * hi;
        float v = acc[n][reg] + mb[qrow * 128 + n * 32 + l31];
        y_s[(wq * 32 + qrow) * 136 + n * 32 + l31] = f2bf(v);
      }
  }
  __syncthreads();

  // W-GEMM: 8 waves x 32 co over this block's 128 q
  const int lr = lane & 15, lg = lane >> 4;
  f32x4 acc2[2][8];
  #pragma unroll
  for (int mm = 0; mm < 2; mm++)
    #pragma unroll
    for (int n = 0; n < 8; n++) acc2[mm][n] = (f32x4)0.0f;

  #pragma unroll
  for (int kk = 0; kk < 4; kk++) {
    short8 af[2], bfr[8];
    #pragma unroll
    for (int mm = 0; mm < 2; mm++)
      af[mm] = *reinterpret_cast<const short8*>(
          ww + (size_t)(wave * 32 + mm * 16 + lr) * 128 + kk * 32 + lg * 8);
    #pragma unroll
    for (int n = 0; n < 8; n++)
      bfr[n] = *reinterpret_cast<const short8*>(
          &y_s[(n * 16 + lr) * 136 + kk * 32 + lg * 8]);
    #pragma unroll
    for (int mm = 0; mm < 2; mm++)
      #pragma unroll
      for (int n = 0; n < 8; n++)
        acc2[mm][n] = MFMA16(af[mm], bfr[n], acc2[mm][n]);
  }

  #pragma unroll
  for (int mm = 0; mm < 2; mm++) {
    #pragma unroll
    for (int n = 0; n < 8; n++) {
      #pragma unroll
      for (int r = 0; r < 4; r++) {
        int co = wave * 32 + mm * 16 + lg * 4 + r;
        int q = q0 + n * 16 + lr;
        size_t oidx = ((size_t)b * 256 + co) * 4096 + q;
        float v = acc2[mm][n][r] * sc_s[co] + sh_s[co];
        out[oidx] = v + x[oidx];
      }
    }
  }
}

// ---------------------------------------------------------------------------
extern "C" void kernel_launch(void* const* d_in, const int* in_sizes, int n_in,
                              void* d_out, int out_size, void* d_ws, size_t ws_size,
                              hipStream_t stream)
{
  const float* x    = (const float*)d_in[0];
  const float* nb   = (const float*)d_in[1];
  const float* g_w  = (const float*)d_in[2];
  const float* g_b  = (const float*)d_in[3];
  const float* th_w = (const float*)d_in[4];
  const float* th_b = (const float*)d_in[5];
  const float* ph_w = (const float*)d_in[6];
  const float* ph_b = (const float*)d_in[7];
  const float* w_w  = (const float*)d_in[8];
  const float* w_b  = (const float*)d_in[9];
  const float* gam  = (const float*)d_in[10];
  const float* bet  = (const float*)d_in[11];
  const float* mu   = (const float*)d_in[12];
  const float* var  = (const float*)d_in[13];
  float* out = (float*)d_out;

  char* ws = (char*)d_ws;
  short* theta_full = (short*)(ws);                        // 8 MB  [b][4096][128]
  short* phi_kc     = (short*)(ws + (size_t)(8u << 20));   // 2 MB  [b][1024][128]
  short* g_ck       = (short*)(ws + (size_t)(10u << 20));  // 2 MB  [b][128][1024]
  short* wts        = (short*)(ws + (size_t)(12u << 20));  // 256KB: th, ph, g, w
  short* th_wb = wts;
  short* ph_wb = wts + 32768;
  short* g_wb  = wts + 2 * 32768;
  short* w_wb  = wts + 3 * 32768;

  cvt_w<<<dim3(32, 4), 256, 0, stream>>>(th_w, ph_w, g_w, w_w, wts);
  conv_all<<<dim3(32, 8, 2), 512, 0, stream>>>(nb, x, th_wb, th_b, ph_wb, ph_b,
                                               g_wb, g_b, theta_full, phi_kc, g_ck);
  attn_wconv<<<dim3(32, 8), 512, 0, stream>>>(theta_full, phi_kc, g_ck, w_wb, w_b,
                                              gam, bet, mu, var, x, out);
}